// Round 1
// baseline (583.333 us; speedup 1.0000x reference)
//
#include <hip/hip_runtime.h>

// Problem constants (B=4, C=128, H=W=96, O=128, 3x3, stride1/pad1/dil1, G=1)
#define BATCH 4
#define CIN   128
#define HH    96
#define WW    96
#define OUTC  128
#define HWSZ  (HH*WW)      // 9216
#define KK    9
#define CKTOT (CIN*KK)     // 1152

// ws layout (float offsets)
#define WT_OFF  0                       // deform weight transposed: [1152][128]
#define WT2_OFF (CKTOT*OUTC)            // 147456: offset(18)+mask(9) weights: [1152][28] (padded)
#define OM_OFF  (WT2_OFF + CKTOT*28)    // 179712: offset/mask maps: [B][27][HW]
// total ws use: 179712 + 4*27*9216 = 1,175,040 floats = 4.7 MB

// ---------------------------------------------------------------------------
// K0: weight transposes.  wt[ck][o] = deform_w[o][ck]; wt2[ck][oc] fused.
// ---------------------------------------------------------------------------
__global__ __launch_bounds__(256) void prep_weights(
    const float* __restrict__ offw, const float* __restrict__ maskw,
    const float* __restrict__ defw, float* __restrict__ ws) {
  int idx = blockIdx.x * 256 + threadIdx.x;
  if (idx < CKTOT * OUTC) {
    int ck = idx >> 7;          // /128
    int o  = idx & 127;
    ws[WT_OFF + ck * OUTC + o] = defw[o * CKTOT + ck];
  } else {
    int j = idx - CKTOT * OUTC;
    if (j < CKTOT * 28) {
      int ck = j / 28, oc = j % 28;
      float v = 0.f;
      if (oc < 18)      v = offw[oc * CKTOT + ck];
      else if (oc < 27) v = maskw[(oc - 18) * CKTOT + ck];
      ws[WT2_OFF + ck * 28 + oc] = v;
    }
  }
}

// ---------------------------------------------------------------------------
// K1: fused offset+mask 3x3 conv (27 out channels), sigmoid on mask channels.
// Block: 256 thr = 4 c-groups x 64 pixels. 576 blocks (= B*HW/64).
// ---------------------------------------------------------------------------
__global__ __launch_bounds__(256) void offmask_conv(
    const float* __restrict__ x2,
    const float* __restrict__ offb, const float* __restrict__ maskb,
    float* __restrict__ ws) {
  __shared__ float red[256 * 29];   // stride 29 -> conflict-free
  int bid  = blockIdx.x;
  int b    = bid / 144;
  int pblk = (bid % 144) * 64;
  int t    = threadIdx.x;
  int pl   = t & 63;
  int cg   = t >> 6;                // wave id: c-range
  int p    = pblk + pl;
  int h = p / WW, w = p % WW;

  const float* wt2 = ws + WT2_OFF;
  float acc[27];
#pragma unroll
  for (int i = 0; i < 27; i++) acc[i] = 0.f;

  for (int cl = 0; cl < 32; cl++) {
    int c = cg * 32 + cl;
    const float* xb = x2 + (size_t)(b * CIN + c) * HWSZ;
    float v[9];
#pragma unroll
    for (int tap = 0; tap < 9; tap++) {
      int ky = tap / 3, kx = tap % 3;
      int y = h + ky - 1, xx = w + kx - 1;
      bool ok = (y >= 0) && (y < HH) && (xx >= 0) && (xx < WW);
      v[tap] = ok ? xb[y * WW + xx] : 0.f;
    }
#pragma unroll
    for (int tap = 0; tap < 9; tap++) {
      const float4* wr = (const float4*)(wt2 + (size_t)(c * 9 + tap) * 28);
      float4 wq[7];
#pragma unroll
      for (int q = 0; q < 7; q++) wq[q] = wr[q];
      const float* wv = (const float*)wq;
#pragma unroll
      for (int oc = 0; oc < 27; oc++) acc[oc] += v[tap] * wv[oc];
    }
  }

#pragma unroll
  for (int oc = 0; oc < 27; oc++) red[t * 29 + oc] = acc[oc];
  __syncthreads();

  for (int e = t; e < 27 * 64; e += 256) {
    int oc = e >> 6, pl2 = e & 63;
    float s = red[(0 * 64 + pl2) * 29 + oc] + red[(1 * 64 + pl2) * 29 + oc]
            + red[(2 * 64 + pl2) * 29 + oc] + red[(3 * 64 + pl2) * 29 + oc];
    if (oc < 18) {
      s += offb[oc];
    } else {
      s += maskb[oc - 18];
      s = 1.f / (1.f + __expf(-s));
    }
    ws[OM_OFF + ((size_t)b * 27 + oc) * HWSZ + pblk + pl2] = s;
  }
}

// ---------------------------------------------------------------------------
// K2: modulated deformable conv. Block: 64 pixels x all 128 outputs.
// Phase A: gather val[144][64] (16-channel chunk) into LDS, lanes<->pixels.
// Phase B: register-tiled fp32 GEMM, thread = 8 px x 4 o accumulators.
// ---------------------------------------------------------------------------
__global__ __launch_bounds__(256) void deform_conv(
    const float* __restrict__ x, const float* __restrict__ defb,
    const float* __restrict__ ws, float* __restrict__ out) {
  __shared__ int   sidx[4][KK * 64];
  __shared__ float swgt[4][KK * 64];
  __shared__ float val[144 * 64];   // 36.9 KB; reused as tbuf[128*66] in epilogue

  int bid  = blockIdx.x;
  int b    = bid / 144;
  int pblk = (bid % 144) * 64;
  int t    = threadIdx.x;

  // --- sampling params per (k, pixel): 4 corner idx + mask-folded weights ---
  const float* om = ws + OM_OFF + (size_t)b * 27 * HWSZ;
  for (int e = t; e < KK * 64; e += 256) {
    int k  = e >> 6;           // 0..8
    int pl = e & 63;
    int p  = pblk + pl;
    int h = p / WW, w = p % WW;
    int ky = k / 3, kx = k % 3;
    float dy = om[(2 * k) * HWSZ + p];
    float dx = om[(2 * k + 1) * HWSZ + p];
    float m  = om[(18 + k) * HWSZ + p];
    float py = (float)(h + ky - 1) + dy;
    float px = (float)(w + kx - 1) + dx;
    float y0f = floorf(py), x0f = floorf(px);
    int y0 = (int)y0f, x0 = (int)x0f;
    float ly = py - y0f, lx = px - x0f;
    int y1 = y0 + 1, x1 = x0 + 1;
    bool vy0 = (y0 >= 0) && (y0 < HH), vy1 = (y1 >= 0) && (y1 < HH);
    bool vx0 = (x0 >= 0) && (x0 < WW), vx1 = (x1 >= 0) && (x1 < WW);
    int cy0 = min(max(y0, 0), HH - 1), cy1 = min(max(y1, 0), HH - 1);
    int cx0 = min(max(x0, 0), WW - 1), cx1 = min(max(x1, 0), WW - 1);
    sidx[0][e] = cy0 * WW + cx0;  swgt[0][e] = (vy0 && vx0) ? m * (1.f - ly) * (1.f - lx) : 0.f;
    sidx[1][e] = cy0 * WW + cx1;  swgt[1][e] = (vy0 && vx1) ? m * (1.f - ly) * lx         : 0.f;
    sidx[2][e] = cy1 * WW + cx0;  swgt[2][e] = (vy1 && vx0) ? m * ly * (1.f - lx)         : 0.f;
    sidx[3][e] = cy1 * WW + cx1;  swgt[3][e] = (vy1 && vx1) ? m * ly * lx                 : 0.f;
  }
  __syncthreads();

  int og = t & 31, pg = t >> 5;       // phase-B roles
  int obase = og * 4;
  int r0 = t >> 6, pl = t & 63;       // phase-A roles
  const float* wt = ws + WT_OFF;

  float acc[8][4];
#pragma unroll
  for (int i = 0; i < 8; i++)
#pragma unroll
    for (int j = 0; j < 4; j++) acc[i][j] = 0.f;

  for (int ch = 0; ch < 8; ch++) {
    int c0 = ch * 16;
    // ---- phase A: gather 16 channels x 9 taps into val[144][64] ----
#pragma unroll
    for (int k = 0; k < KK; k++) {
      int e = k * 64 + pl;
      int   i00 = sidx[0][e], i01 = sidx[1][e], i10 = sidx[2][e], i11 = sidx[3][e];
      float w00 = swgt[0][e], w01 = swgt[1][e], w10 = swgt[2][e], w11 = swgt[3][e];
#pragma unroll
      for (int cl = 0; cl < 4; cl++) {
        int c = c0 + r0 * 4 + cl;
        const float* xb = x + (size_t)(b * CIN + c) * HWSZ;
        float vv = w00 * xb[i00] + w01 * xb[i01] + w10 * xb[i10] + w11 * xb[i11];
        val[((r0 * 4 + cl) * KK + k) * 64 + pl] = vv;
      }
    }
    __syncthreads();

    // ---- phase B: acc[8px][4o] += val[ck][px] * wt[ck][o] ----
    const float* wrow = wt + (size_t)(c0 * KK) * OUTC + obase;
    const float* vrow = val + pg * 8;
    for (int ck = 0; ck < 144; ck++) {
      float4 wv = *(const float4*)wrow;
      float4 v0 = *(const float4*)vrow;
      float4 v1 = *(const float4*)(vrow + 4);
      float vv[8] = {v0.x, v0.y, v0.z, v0.w, v1.x, v1.y, v1.z, v1.w};
#pragma unroll
      for (int i = 0; i < 8; i++) {
        acc[i][0] += vv[i] * wv.x;
        acc[i][1] += vv[i] * wv.y;
        acc[i][2] += vv[i] * wv.z;
        acc[i][3] += vv[i] * wv.w;
      }
      wrow += OUTC;
      vrow += 64;
    }
    __syncthreads();   // val will be overwritten by next chunk (or epilogue)
  }

  // ---- epilogue: bias, transpose via LDS so stores are coalesced ----
  float4 bb = *(const float4*)(defb + obase);
  float* tbuf = val;                  // 128*66 = 8448 <= 9216
#pragma unroll
  for (int i = 0; i < 8; i++) {
    int plx = pg * 8 + i;
    tbuf[(obase + 0) * 66 + plx] = acc[i][0] + bb.x;
    tbuf[(obase + 1) * 66 + plx] = acc[i][1] + bb.y;
    tbuf[(obase + 2) * 66 + plx] = acc[i][2] + bb.z;
    tbuf[(obase + 3) * 66 + plx] = acc[i][3] + bb.w;
  }
  __syncthreads();
  for (int e = t; e < 64 * OUTC; e += 256) {
    int o = e >> 6, plx = e & 63;
    out[((size_t)(b * OUTC + o)) * HWSZ + pblk + plx] = tbuf[o * 66 + plx];
  }
}

// ---------------------------------------------------------------------------
extern "C" void kernel_launch(void* const* d_in, const int* in_sizes, int n_in,
                              void* d_out, int out_size, void* d_ws, size_t ws_size,
                              hipStream_t stream) {
  const float* x     = (const float*)d_in[0];
  const float* x2    = (const float*)d_in[1];
  const float* offw  = (const float*)d_in[2];
  const float* offb  = (const float*)d_in[3];
  const float* maskw = (const float*)d_in[4];
  const float* maskb = (const float*)d_in[5];
  const float* defw  = (const float*)d_in[6];
  const float* defb  = (const float*)d_in[7];
  float* out = (float*)d_out;
  float* ws  = (float*)d_ws;

  // K0: 147456 + 32256 = 179712 threads = 702 blocks exactly
  hipLaunchKernelGGL(prep_weights, dim3(702), dim3(256), 0, stream, offw, maskw, defw, ws);
  // K1/K2: B*HW/64 = 576 blocks
  hipLaunchKernelGGL(offmask_conv, dim3(576), dim3(256), 0, stream, x2, offb, maskb, ws);
  hipLaunchKernelGGL(deform_conv,  dim3(576), dim3(256), 0, stream, x, defb, ws, out);
}

// Round 2
// 311.724 us; speedup vs baseline: 1.8713x; 1.8713x over previous
//
#include <hip/hip_runtime.h>

// DeformConv fused: offset/mask conv + modulated deformable conv, bf16 MFMA.
// B=4, C=128, H=W=96, O=128, 3x3 s1 p1 d1, G=1.
#define CIN   128
#define HH    96
#define WW    96
#define OUTC  128
#define HWSZ  9216
#define KK    9
#define KTOT  1152        // C*9; K order is k' = tap*128 + c (tap-major!)

typedef __bf16 bf16x8 __attribute__((ext_vector_type(8)));
typedef float  f32x4  __attribute__((ext_vector_type(4)));

__device__ __forceinline__ unsigned short f2bf(float f) {
  unsigned u = __builtin_bit_cast(unsigned, f);
  u += 0x7fffu + ((u >> 16) & 1u);               // RNE
  return (unsigned short)(u >> 16);
}
__device__ __forceinline__ float bf2f(unsigned u16) {
  unsigned u = u16 << 16;
  return __builtin_bit_cast(float, u);
}

// ws layout (bytes):
//   wtb  : bf16 [128 o][1152 k']      @ 0        (294912 B)   k' = tap*128+c
//   wt2b : bf16 [32 oc][1152 k']      @ 294912   (73728 B)    oc: 0-17 off, 18-26 mask, 27-31 zero
//   bias32: f32 [32]                  @ 368640   (128 B)
__global__ __launch_bounds__(256) void prep(
    const float* __restrict__ offw, const float* __restrict__ maskw,
    const float* __restrict__ defw, const float* __restrict__ offb,
    const float* __restrict__ maskb, void* __restrict__ wsv) {
  unsigned short* wtb  = (unsigned short*)wsv;
  unsigned short* wt2b = wtb + OUTC * KTOT;
  float* bias32 = (float*)(wt2b + 32 * KTOT);
  int idx = blockIdx.x * 256 + threadIdx.x;
  if (idx < OUTC * KTOT) {
    int o = idx / KTOT, r = idx % KTOT;
    int tap = r >> 7, c = r & 127;
    wtb[idx] = f2bf(defw[o * KTOT + c * KK + tap]);
  } else if (idx < OUTC * KTOT + 32 * KTOT) {
    int j = idx - OUTC * KTOT;
    int oc = j / KTOT, r = j % KTOT;
    int tap = r >> 7, c = r & 127;
    float v = 0.f;
    if (oc < 18)      v = offw[oc * KTOT + c * KK + tap];
    else if (oc < 27) v = maskw[(oc - 18) * KTOT + c * KK + tap];
    wt2b[j] = f2bf(v);
  } else if (idx < OUTC * KTOT + 32 * KTOT + 32) {
    int j = idx - OUTC * KTOT - 32 * KTOT;
    float v = 0.f;
    if (j < 18) v = offb[j]; else if (j < 27) v = maskb[j - 18];
    bias32[j] = v;
  }
}

// One block = 64 consecutive pixels of one batch image, all 128 outputs.
// Phases: (1) om GEMM (x2 im2col -> offsets/mask, MFMA, N=32)
//         (2) params: bilinear corners+weights per (tap,px) -> LDS
//         (3) main: per tap: gather 128ch bilinear (bf16) -> LDS, MFMA
//         (4) epilogue: bias + LDS transpose -> coalesced float4 stores
__global__ __launch_bounds__(256, 4) void fused(
    const float* __restrict__ x, const float* __restrict__ x2,
    const float* __restrict__ defb, const void* __restrict__ wsv,
    float* __restrict__ out) {
  const unsigned short* wtb  = (const unsigned short*)wsv;
  const unsigned short* wt2b = wtb + OUTC * KTOT;
  const float* bias32 = (const float*)(wt2b + 32 * KTOT);

  __shared__ unsigned short val[64][136];  // bf16 bits; stride 136 (16B-aligned, odd*8)
  __shared__ float om[32][68];             // om dump; reused as transpose buf in epilogue
  __shared__ uint4 prm[KK * 64];           // packed: 4 u16 idx + 4 bf16 corner wgts

  int t = threadIdx.x;
  int w = t >> 6;                 // wave 0..3
  int l = t & 63;
  int l15 = l & 15, quad = l >> 4;
  int bid = blockIdx.x;
  int b = bid / 144;
  int pblk = (bid % 144) * 64;

  int px = t & 63;                // gather role: pixel
  int cq = t >> 6;                // gather role: channel quarter (32 ch)
  int p = pblk + px;
  int ph = p / WW, pw = p % WW;

  // ---------------- phase 1: offset/mask GEMM ----------------
  f32x4 oacc0 = {0.f, 0.f, 0.f, 0.f};
  f32x4 oacc1 = {0.f, 0.f, 0.f, 0.f};
  for (int tap = 0; tap < KK; ++tap) {
    int ky = tap / 3 - 1, kx = tap % 3 - 1;
    int y = ph + ky, xx = pw + kx;
    bool ok = (y >= 0) && (y < HH) && (xx >= 0) && (xx < WW);
    const float* xc = x2 + ((size_t)b * CIN + cq * 32) * HWSZ + (ok ? (y * WW + xx) : 0);
    float zf = ok ? 1.f : 0.f;
    for (int g = 0; g < 4; ++g) {
      unsigned pk[4];
#pragma unroll
      for (int j = 0; j < 4; ++j) {
        float v0 = xc[(size_t)(g * 8 + 2 * j)     * HWSZ] * zf;
        float v1 = xc[(size_t)(g * 8 + 2 * j + 1) * HWSZ] * zf;
        pk[j] = (unsigned)f2bf(v0) | ((unsigned)f2bf(v1) << 16);
      }
      *(uint4*)&val[px][cq * 32 + g * 8] = make_uint4(pk[0], pk[1], pk[2], pk[3]);
    }
    __syncthreads();
    // wave w computes m-tile w (16 px) x 32 oc
    const unsigned short* vrow = &val[w * 16 + l15][0];
#pragma unroll
    for (int ks = 0; ks < 4; ++ks) {
      bf16x8 af = *(const bf16x8*)(vrow + ks * 32 + quad * 8);
      int k0 = tap * 128 + ks * 32 + quad * 8;
      bf16x8 b0 = *(const bf16x8*)(wt2b + (size_t)(l15)      * KTOT + k0);
      bf16x8 b1 = *(const bf16x8*)(wt2b + (size_t)(l15 + 16) * KTOT + k0);
      oacc0 = __builtin_amdgcn_mfma_f32_16x16x32_bf16(af, b0, oacc0, 0, 0, 0);
      oacc1 = __builtin_amdgcn_mfma_f32_16x16x32_bf16(af, b1, oacc1, 0, 0, 0);
    }
    __syncthreads();
  }
  // dump om (+bias): C layout col=lane&15 (oc), row=quad*4+reg (px within m-tile)
#pragma unroll
  for (int nt = 0; nt < 2; ++nt) {
    f32x4 a = nt ? oacc1 : oacc0;
    int oc = nt * 16 + l15;
    float bia = bias32[oc];
#pragma unroll
    for (int r = 0; r < 4; ++r)
      om[oc][w * 16 + quad * 4 + r] = a[r] + bia;
  }
  __syncthreads();

  // ---------------- phase 2: bilinear params ----------------
  for (int e = t; e < KK * 64; e += 256) {
    int tap = e >> 6, pp = e & 63;
    int gp = pblk + pp;
    int h = gp / WW, ww_ = gp % WW;
    float dy = om[2 * tap][pp], dx = om[2 * tap + 1][pp];
    float mr = om[18 + tap][pp];
    float m = 1.f / (1.f + __expf(-mr));
    float py  = (float)(h + tap / 3 - 1) + dy;
    float pxx = (float)(ww_ + tap % 3 - 1) + dx;
    float y0f = floorf(py), x0f = floorf(pxx);
    int y0 = (int)y0f, x0 = (int)x0f;
    float ly = py - y0f, lx = pxx - x0f;
    int y1 = y0 + 1, x1 = x0 + 1;
    bool vy0 = (unsigned)y0 < HH, vy1 = (unsigned)y1 < HH;
    bool vx0 = (unsigned)x0 < WW, vx1 = (unsigned)x1 < WW;
    int cy0 = min(max(y0, 0), HH - 1), cy1 = min(max(y1, 0), HH - 1);
    int cx0 = min(max(x0, 0), WW - 1), cx1 = min(max(x1, 0), WW - 1);
    unsigned i00 = cy0 * WW + cx0, i01 = cy0 * WW + cx1;
    unsigned i10 = cy1 * WW + cx0, i11 = cy1 * WW + cx1;
    float w00 = (vy0 && vx0) ? m * (1.f - ly) * (1.f - lx) : 0.f;
    float w01 = (vy0 && vx1) ? m * (1.f - ly) * lx         : 0.f;
    float w10 = (vy1 && vx0) ? m * ly * (1.f - lx)         : 0.f;
    float w11 = (vy1 && vx1) ? m * ly * lx                 : 0.f;
    uint4 pk;
    pk.x = i00 | (i01 << 16);
    pk.y = i10 | (i11 << 16);
    pk.z = (unsigned)f2bf(w00) | ((unsigned)f2bf(w01) << 16);
    pk.w = (unsigned)f2bf(w10) | ((unsigned)f2bf(w11) << 16);
    prm[e] = pk;
  }
  __syncthreads();

  // ---------------- phase 3: main deformable GEMM ----------------
  f32x4 acc[4][2];
#pragma unroll
  for (int mt = 0; mt < 4; ++mt) {
    acc[mt][0] = (f32x4){0.f, 0.f, 0.f, 0.f};
    acc[mt][1] = (f32x4){0.f, 0.f, 0.f, 0.f};
  }
  const float* xbase = x + ((size_t)b * CIN + cq * 32) * HWSZ;
  for (int tap = 0; tap < KK; ++tap) {
    uint4 pk = prm[tap * 64 + px];
    unsigned i00 = pk.x & 0xffffu, i01 = pk.x >> 16;
    unsigned i10 = pk.y & 0xffffu, i11 = pk.y >> 16;
    float w00 = bf2f(pk.z & 0xffffu), w01 = bf2f(pk.z >> 16);
    float w10 = bf2f(pk.w & 0xffffu), w11 = bf2f(pk.w >> 16);
    for (int g = 0; g < 4; ++g) {
      unsigned pkk[4];
#pragma unroll
      for (int j = 0; j < 4; ++j) {
        const float* c0p = xbase + (size_t)(g * 8 + 2 * j) * HWSZ;
        const float* c1p = c0p + HWSZ;
        float v0 = w00 * c0p[i00] + w01 * c0p[i01] + w10 * c0p[i10] + w11 * c0p[i11];
        float v1 = w00 * c1p[i00] + w01 * c1p[i01] + w10 * c1p[i10] + w11 * c1p[i11];
        pkk[j] = (unsigned)f2bf(v0) | ((unsigned)f2bf(v1) << 16);
      }
      *(uint4*)&val[px][cq * 32 + g * 8] = make_uint4(pkk[0], pkk[1], pkk[2], pkk[3]);
    }
    __syncthreads();
    // wave w: all 4 m-tiles x its 32-o strip (2 n-tiles)
#pragma unroll
    for (int ks = 0; ks < 4; ++ks) {
      int k0 = tap * 128 + ks * 32 + quad * 8;
      bf16x8 bb0 = *(const bf16x8*)(wtb + (size_t)(w * 32 + l15)      * KTOT + k0);
      bf16x8 bb1 = *(const bf16x8*)(wtb + (size_t)(w * 32 + 16 + l15) * KTOT + k0);
#pragma unroll
      for (int mt = 0; mt < 4; ++mt) {
        bf16x8 aa = *(const bf16x8*)(&val[mt * 16 + l15][ks * 32 + quad * 8]);
        acc[mt][0] = __builtin_amdgcn_mfma_f32_16x16x32_bf16(aa, bb0, acc[mt][0], 0, 0, 0);
        acc[mt][1] = __builtin_amdgcn_mfma_f32_16x16x32_bf16(aa, bb1, acc[mt][1], 0, 0, 0);
      }
    }
    __syncthreads();
  }

  // ---------------- phase 4: epilogue ----------------
  float db0 = defb[w * 32 + l15];
  float db1 = defb[w * 32 + 16 + l15];
  for (int r = 0; r < 4; ++r) {
    if (w == r) {
#pragma unroll
      for (int mt = 0; mt < 4; ++mt) {
#pragma unroll
        for (int reg = 0; reg < 4; ++reg) {
          om[l15]     [mt * 16 + quad * 4 + reg] = acc[mt][0][reg] + db0;
          om[16 + l15][mt * 16 + quad * 4 + reg] = acc[mt][1][reg] + db1;
        }
      }
    }
    __syncthreads();
    int row = t >> 4;               // 0..15
    int col4 = (t & 15) * 4;
#pragma unroll
    for (int hrow = 0; hrow < 2; ++hrow) {
      int rr = row + hrow * 16;
      float4 v = *(float4*)&om[rr][col4];
      *(float4*)&out[((size_t)b * OUTC + r * 32 + rr) * HWSZ + pblk + col4] = v;
    }
    __syncthreads();
  }
}

extern "C" void kernel_launch(void* const* d_in, const int* in_sizes, int n_in,
                              void* d_out, int out_size, void* d_ws, size_t ws_size,
                              hipStream_t stream) {
  const float* x     = (const float*)d_in[0];
  const float* x2    = (const float*)d_in[1];
  const float* offw  = (const float*)d_in[2];
  const float* offb  = (const float*)d_in[3];
  const float* maskw = (const float*)d_in[4];
  const float* maskb = (const float*)d_in[5];
  const float* defw  = (const float*)d_in[6];
  const float* defb  = (const float*)d_in[7];
  float* out = (float*)d_out;

  // prep: 147456 + 36864 + 32 = 184352 elems -> 721 blocks
  hipLaunchKernelGGL(prep, dim3(721), dim3(256), 0, stream,
                     offw, maskw, defw, offb, maskb, d_ws);
  // fused: B*HW/64 = 576 blocks
  hipLaunchKernelGGL(fused, dim3(576), dim3(256), 0, stream,
                     x, x2, defb, d_ws, out);
}

// Round 3
// 280.003 us; speedup vs baseline: 2.0833x; 1.1133x over previous
//
#include <hip/hip_runtime.h>

// DeformConv fused: offset/mask conv + modulated deformable conv, bf16 MFMA.
// B=4, C=128, H=W=96, O=128, 3x3 s1 p1 d1, G=1.
#define CIN   128
#define HH    96
#define WW    96
#define OUTC  128
#define HWSZ  9216
#define KK    9
#define KTOT  1152        // C*9; K order is k' = tap*128 + c (tap-major!)

typedef __bf16 bf16x8 __attribute__((ext_vector_type(8)));
typedef float  f32x4  __attribute__((ext_vector_type(4)));

__device__ __forceinline__ unsigned short f2bf(float f) {
  unsigned u = __builtin_bit_cast(unsigned, f);
  u += 0x7fffu + ((u >> 16) & 1u);               // RNE
  return (unsigned short)(u >> 16);
}
__device__ __forceinline__ float bf2f_lo(unsigned w) {   // low 16 bits -> float
  unsigned u = w << 16;
  return __builtin_bit_cast(float, u);
}
__device__ __forceinline__ float bf2f_hi(unsigned w) {   // high 16 bits -> float
  unsigned u = w & 0xffff0000u;
  return __builtin_bit_cast(float, u);
}
// pack two floats to bf16x2 (round-half-up: +0x8000 then truncate) in 3 VALU
__device__ __forceinline__ unsigned pack_bf(float v0, float v1) {
  unsigned u0 = __builtin_bit_cast(unsigned, v0) + 0x8000u;
  unsigned u1 = __builtin_bit_cast(unsigned, v1) + 0x8000u;
  return __builtin_amdgcn_perm(u1, u0, 0x07060302u);   // {hi16(u1),hi16(u0)}
}

// ws layout:
//   wtb  : bf16 [128 o][1152 k']   @ 0          k' = tap*128+c
//   wt2b : bf16 [32 oc][1152 k']   @ +128*1152  oc: 0-17 off, 18-26 mask, 27-31 zero
//   bias32: f32 [32]               @ +32*1152
__global__ __launch_bounds__(256) void prep(
    const float* __restrict__ offw, const float* __restrict__ maskw,
    const float* __restrict__ defw, const float* __restrict__ offb,
    const float* __restrict__ maskb, void* __restrict__ wsv) {
  unsigned short* wtb  = (unsigned short*)wsv;
  unsigned short* wt2b = wtb + OUTC * KTOT;
  float* bias32 = (float*)(wt2b + 32 * KTOT);
  int idx = blockIdx.x * 256 + threadIdx.x;
  if (idx < OUTC * KTOT) {
    int o = idx / KTOT, r = idx - o * KTOT;
    int c = r / KK, tap = r - c * KK;
    wtb[o * KTOT + tap * 128 + c] = f2bf(defw[idx]);     // coalesced read
  } else if (idx < OUTC * KTOT + 32 * KTOT) {
    int j = idx - OUTC * KTOT;
    int oc = j / KTOT, r = j - oc * KTOT;
    int c = r / KK, tap = r - c * KK;
    float v = 0.f;
    if (oc < 18)      v = offw[j];
    else if (oc < 27) v = maskw[j - 18 * KTOT];
    wt2b[oc * KTOT + tap * 128 + c] = f2bf(v);
  } else if (idx < OUTC * KTOT + 32 * KTOT + 32) {
    int j = idx - OUTC * KTOT - 32 * KTOT;
    float v = 0.f;
    if (j < 18) v = offb[j]; else if (j < 27) v = maskb[j - 18];
    bias32[j] = v;
  }
}

// One block = 64 consecutive pixels of one image, all 128 outputs.
// XCD-swizzled so same-XCD blocks cover contiguous strips (L2 residency).
// val double-buffered: gather tap+1 issues before tap's MFMAs, 1 barrier/tap.
__global__ __launch_bounds__(256, 2) void fused(
    const float* __restrict__ x, const float* __restrict__ x2,
    const float* __restrict__ defb, const void* __restrict__ wsv,
    float* __restrict__ out) {
  const unsigned short* wtb  = (const unsigned short*)wsv;
  const unsigned short* wt2b = wtb + OUTC * KTOT;
  const float* bias32 = (const float*)(wt2b + 32 * KTOT);

  __shared__ unsigned short val[2][64][136];  // 34.8 KB, stride 136 (16B-aligned)
  __shared__ float om[32][68];                // 8.7 KB; reused as transpose buf
  __shared__ uint4 prm[KK * 64];              // 9.2 KB

  int t = threadIdx.x;
  int w = t >> 6;                     // wave 0..3
  int l15 = t & 15, quad = (t >> 4) & 3;
  // XCD swizzle: round-robin dispatch => blockIdx%8 = XCD; give each XCD
  // 72 consecutive strips (same image region) so x/x2 stay L2-resident.
  int rb = blockIdx.x;
  int bid = (rb & 7) * 72 + (rb >> 3);
  int b = bid / 144;
  int pblk = (bid % 144) * 64;

  int px = t & 63;                    // gather role: pixel
  int cq = t >> 6;                    // gather role: 32-channel group
  int p = pblk + px;
  int ph = p / WW, pw = p % WW;

  // ================= phase 1: offset/mask GEMM (x2) =================
  const float* x2base = x2 + ((size_t)b * CIN + cq * 32) * HWSZ;
  {
    int y = ph - 1, xx = pw - 1;
    bool ok = ((unsigned)y < HH) && ((unsigned)xx < WW);
    const float* xc = x2base + (ok ? (y * WW + xx) : 0);
    float r[32];
#pragma unroll
    for (int c = 0; c < 32; ++c) r[c] = xc[(size_t)c * HWSZ];
    unsigned pk[16];
#pragma unroll
    for (int q = 0; q < 16; ++q)
      pk[q] = ok ? pack_bf(r[2 * q], r[2 * q + 1]) : 0u;
#pragma unroll
    for (int q4 = 0; q4 < 4; ++q4)
      *(uint4*)&val[0][px][cq * 32 + q4 * 8] =
          make_uint4(pk[4 * q4], pk[4 * q4 + 1], pk[4 * q4 + 2], pk[4 * q4 + 3]);
  }
  __syncthreads();

  f32x4 oacc0 = {0.f, 0.f, 0.f, 0.f};
  f32x4 oacc1 = {0.f, 0.f, 0.f, 0.f};
  for (int tap = 0; tap < KK; ++tap) {
    int cur = tap & 1;
    float r[32];
    bool ok = false;
    if (tap < 8) {                       // issue tap+1 loads first
      int tn = tap + 1;
      int y = ph + tn / 3 - 1, xx = pw + tn % 3 - 1;
      ok = ((unsigned)y < HH) && ((unsigned)xx < WW);
      const float* xc = x2base + (ok ? (y * WW + xx) : 0);
#pragma unroll
      for (int c = 0; c < 32; ++c) r[c] = xc[(size_t)c * HWSZ];
    }
    const unsigned short* vrow = &val[cur][w * 16 + l15][0];
#pragma unroll
    for (int ks = 0; ks < 4; ++ks) {
      bf16x8 af = *(const bf16x8*)(vrow + ks * 32 + quad * 8);
      int k0 = tap * 128 + ks * 32 + quad * 8;
      bf16x8 b0 = *(const bf16x8*)(wt2b + (size_t)l15 * KTOT + k0);
      bf16x8 b1 = *(const bf16x8*)(wt2b + (size_t)(l15 + 16) * KTOT + k0);
      oacc0 = __builtin_amdgcn_mfma_f32_16x16x32_bf16(af, b0, oacc0, 0, 0, 0);
      oacc1 = __builtin_amdgcn_mfma_f32_16x16x32_bf16(af, b1, oacc1, 0, 0, 0);
    }
    if (tap < 8) {
      unsigned pk[16];
#pragma unroll
      for (int q = 0; q < 16; ++q)
        pk[q] = ok ? pack_bf(r[2 * q], r[2 * q + 1]) : 0u;
#pragma unroll
      for (int q4 = 0; q4 < 4; ++q4)
        *(uint4*)&val[cur ^ 1][px][cq * 32 + q4 * 8] =
            make_uint4(pk[4 * q4], pk[4 * q4 + 1], pk[4 * q4 + 2], pk[4 * q4 + 3]);
    }
    __syncthreads();
  }
  // dump om (+bias): C layout col=lane&15 (oc), row=quad*4+reg (px in m-tile)
#pragma unroll
  for (int nt = 0; nt < 2; ++nt) {
    f32x4 a = nt ? oacc1 : oacc0;
    int oc = nt * 16 + l15;
    float bia = bias32[oc];
#pragma unroll
    for (int r = 0; r < 4; ++r)
      om[oc][w * 16 + quad * 4 + r] = a[r] + bia;
  }
  __syncthreads();

  // ================= phase 2: bilinear params =================
  for (int e = t; e < KK * 64; e += 256) {
    int tap = e >> 6, pp = e & 63;
    int gp = pblk + pp;
    int h = gp / WW, ww_ = gp % WW;
    float dy = om[2 * tap][pp], dx = om[2 * tap + 1][pp];
    float mr = om[18 + tap][pp];
    float m = 1.f / (1.f + __expf(-mr));
    float py  = (float)(h + tap / 3 - 1) + dy;
    float pxx = (float)(ww_ + tap % 3 - 1) + dx;
    float y0f = floorf(py), x0f = floorf(pxx);
    int y0 = (int)y0f, x0 = (int)x0f;
    float ly = py - y0f, lx = pxx - x0f;
    int y1 = y0 + 1, x1 = x0 + 1;
    bool vy0 = (unsigned)y0 < HH, vy1 = (unsigned)y1 < HH;
    bool vx0 = (unsigned)x0 < WW, vx1 = (unsigned)x1 < WW;
    int cy0 = min(max(y0, 0), HH - 1), cy1 = min(max(y1, 0), HH - 1);
    int cx0 = min(max(x0, 0), WW - 1), cx1 = min(max(x1, 0), WW - 1);
    unsigned i00 = cy0 * WW + cx0, i01 = cy0 * WW + cx1;
    unsigned i10 = cy1 * WW + cx0, i11 = cy1 * WW + cx1;
    float w00 = (vy0 && vx0) ? m * (1.f - ly) * (1.f - lx) : 0.f;
    float w01 = (vy0 && vx1) ? m * (1.f - ly) * lx         : 0.f;
    float w10 = (vy1 && vx0) ? m * ly * (1.f - lx)         : 0.f;
    float w11 = (vy1 && vx1) ? m * ly * lx                 : 0.f;
    uint4 pk;
    pk.x = i00 | (i01 << 16);
    pk.y = i10 | (i11 << 16);
    pk.z = (unsigned)f2bf(w00) | ((unsigned)f2bf(w01) << 16);
    pk.w = (unsigned)f2bf(w10) | ((unsigned)f2bf(w11) << 16);
    prm[e] = pk;
  }
  __syncthreads();

  // ================= phase 3: main deformable GEMM =================
  f32x4 acc[4][2];
#pragma unroll
  for (int mt = 0; mt < 4; ++mt) {
    acc[mt][0] = (f32x4){0.f, 0.f, 0.f, 0.f};
    acc[mt][1] = (f32x4){0.f, 0.f, 0.f, 0.f};
  }
  const float* xbase = x + ((size_t)b * CIN + cq * 32) * HWSZ;

  unsigned i00, i01, i10, i11;
  float w00, w01, w10, w11;
  auto unpack_prm = [&](int tap) {
    uint4 pk = prm[tap * 64 + px];
    i00 = pk.x & 0xffffu; i01 = pk.x >> 16;
    i10 = pk.y & 0xffffu; i11 = pk.y >> 16;
    w00 = bf2f_lo(pk.z);  w01 = bf2f_hi(pk.z);
    w10 = bf2f_lo(pk.w);  w11 = bf2f_hi(pk.w);
  };
  auto load_half = [&](int h, float* r) {
    const float* cb = xbase + (size_t)(h * 16) * HWSZ;
#pragma unroll
    for (int c = 0; c < 16; ++c) {
      const float* pc = cb + (size_t)c * HWSZ;
      r[4 * c + 0] = pc[i00]; r[4 * c + 1] = pc[i01];
      r[4 * c + 2] = pc[i10]; r[4 * c + 3] = pc[i11];
    }
  };
  auto pack_half = [&](int nb, int h, const float* r) {
    unsigned pk[8];
#pragma unroll
    for (int q = 0; q < 8; ++q) {
      float v0 = w00 * r[8*q+0] + w01 * r[8*q+1] + w10 * r[8*q+2] + w11 * r[8*q+3];
      float v1 = w00 * r[8*q+4] + w01 * r[8*q+5] + w10 * r[8*q+6] + w11 * r[8*q+7];
      pk[q] = pack_bf(v0, v1);
    }
    *(uint4*)&val[nb][px][cq * 32 + h * 16]     = make_uint4(pk[0], pk[1], pk[2], pk[3]);
    *(uint4*)&val[nb][px][cq * 32 + h * 16 + 8] = make_uint4(pk[4], pk[5], pk[6], pk[7]);
  };
  auto mfma_half = [&](int cur, int tap, int s) {
#pragma unroll
    for (int ks = s; ks < s + 2; ++ks) {
      int k0 = tap * 128 + ks * 32 + quad * 8;
      bf16x8 bb0 = *(const bf16x8*)(wtb + (size_t)(w * 32 + l15)      * KTOT + k0);
      bf16x8 bb1 = *(const bf16x8*)(wtb + (size_t)(w * 32 + 16 + l15) * KTOT + k0);
#pragma unroll
      for (int mt = 0; mt < 4; ++mt) {
        bf16x8 aa = *(const bf16x8*)(&val[cur][mt * 16 + l15][ks * 32 + quad * 8]);
        acc[mt][0] = __builtin_amdgcn_mfma_f32_16x16x32_bf16(aa, bb0, acc[mt][0], 0, 0, 0);
        acc[mt][1] = __builtin_amdgcn_mfma_f32_16x16x32_bf16(aa, bb1, acc[mt][1], 0, 0, 0);
      }
    }
  };

  // prologue: gather tap 0 -> val[0]
  unpack_prm(0);
  {
    float r[64];
#pragma unroll
    for (int h = 0; h < 2; ++h) {
      load_half(h, r);
      pack_half(0, h, r);
    }
  }
  __syncthreads();

  for (int tap = 0; tap < KK; ++tap) {
    int cur = tap & 1;
    if (tap < 8) unpack_prm(tap + 1);
    float r0[64], r1[64];
    if (tap < 8) load_half(0, r0);        // loads in flight during MFMAs
    mfma_half(cur, tap, 0);
    if (tap < 8) { pack_half(cur ^ 1, 0, r0); load_half(1, r1); }
    mfma_half(cur, tap, 2);
    if (tap < 8) pack_half(cur ^ 1, 1, r1);
    __syncthreads();
  }

  // ================= phase 4: epilogue =================
  float db0 = defb[w * 32 + l15];
  float db1 = defb[w * 32 + 16 + l15];
  for (int r = 0; r < 4; ++r) {
    if (w == r) {
#pragma unroll
      for (int mt = 0; mt < 4; ++mt) {
#pragma unroll
        for (int reg = 0; reg < 4; ++reg) {
          om[l15]     [mt * 16 + quad * 4 + reg] = acc[mt][0][reg] + db0;
          om[16 + l15][mt * 16 + quad * 4 + reg] = acc[mt][1][reg] + db1;
        }
      }
    }
    __syncthreads();
    int row = t >> 4;               // 0..15
    int col4 = (t & 15) * 4;
#pragma unroll
    for (int hrow = 0; hrow < 2; ++hrow) {
      int rr = row + hrow * 16;
      float4 v = *(float4*)&om[rr][col4];
      *(float4*)&out[((size_t)b * OUTC + r * 32 + rr) * HWSZ + pblk + col4] = v;
    }
    __syncthreads();
  }
}

extern "C" void kernel_launch(void* const* d_in, const int* in_sizes, int n_in,
                              void* d_out, int out_size, void* d_ws, size_t ws_size,
                              hipStream_t stream) {
  const float* x     = (const float*)d_in[0];
  const float* x2    = (const float*)d_in[1];
  const float* offw  = (const float*)d_in[2];
  const float* offb  = (const float*)d_in[3];
  const float* maskw = (const float*)d_in[4];
  const float* maskb = (const float*)d_in[5];
  const float* defw  = (const float*)d_in[6];
  const float* defb  = (const float*)d_in[7];
  float* out = (float*)d_out;

  // prep: 147456 + 36864 + 32 = 184352 elems -> 721 blocks
  hipLaunchKernelGGL(prep, dim3(721), dim3(256), 0, stream,
                     offw, maskw, defw, offb, maskb, d_ws);
  // fused: B*HW/64 = 576 blocks (8 XCDs x 72)
  hipLaunchKernelGGL(fused, dim3(576), dim3(256), 0, stream,
                     x, x2, defb, d_ws, out);
}